// Round 9
// baseline (4095.156 us; speedup 1.0000x reference)
//
#include <hip/hip_runtime.h>
#include <hip/hip_bf16.h>
#include <stdint.h>

typedef unsigned short u16;
typedef unsigned char u8;
typedef float f32x4 __attribute__((ext_vector_type(4)));
typedef float f32x2 __attribute__((ext_vector_type(2)));
typedef _Float16 f16x2 __attribute__((ext_vector_type(2)));
typedef _Float16 f16x8 __attribute__((ext_vector_type(8)));
typedef long lx2 __attribute__((ext_vector_type(2)));

#define H      300
#define KP     320          // K padded (320 fp8 bytes per row)
#define BATCH  256
#define NX     128
#define NY     128
#define VY     32000
#define NPAD   32768        // vocab padded
#define MROWS  32512        // 127*256 decoder rows

// Swizzled OW layout (OWS), tc-pair INTERLEAVED (R7): vocab col v, k ->
// tile = v>>6 (64 cols x 320 K = 20480 B each); within tile:
//   byte = (k>>5)*2048 + ((v>>5)&1)*1024
//        + ((v&15) + ((k>>3)&3)*16)*16 + ((v>>4)&1)*8 + (k&7)
// A lane's ds_read_b128 at [ks*2048 + tcp*1024 + lane*16] returns the b64
// MFMA B-fragments of BOTH tc=2*tcp and tc=2*tcp+1.
// Staging remains a LINEAR 20480B tile copy (swizzle-agnostic).

// workspace layout (bytes)
#define OWS_OFF   0UL
#define OWS_BYTES ((unsigned long)NPAD * KP)           // 10,485,760
#define OWS_PAD   131072UL
#define A8_OFF    (OWS_OFF + OWS_BYTES + OWS_PAD)
#define A8_BYTES  ((unsigned long)MROWS * KP)          // 10,403,840
#define WTE_OFF   (A8_OFF + A8_BYTES)
#define WT_BYTES  (320UL * KP * 4)                     // 320 rows (zero-pad k>=300)
#define WTD_OFF   (WTE_OFF + WT_BYTES)
#define OBP_OFF   (WTD_OFF + WT_BYTES)
#define OBP_BYTES ((unsigned long)NPAD * 4)            // eob = exp(outb), pad = 0
#define SE_OFF    (OBP_OFF + OBP_BYTES)
#define SE_BYTES  ((unsigned long)MROWS * 4)

// async 16B global -> LDS copy (LDS dst is wave-uniform base; HW adds lane*16)
#define ASYNC_COPY16(dst_lds, src_glb)                                          \
    __builtin_amdgcn_global_load_lds(                                           \
        (const __attribute__((address_space(1))) unsigned int*)(src_glb),       \
        (__attribute__((address_space(3))) unsigned int*)(dst_lds), 16, 0, 0)

// ---------------- K0: prep (fp8 outW -> swizzled OWS; eob; W^T) ----------
__global__ __launch_bounds__(256) void k0_prep(const float* __restrict__ outW,
                                               const float* __restrict__ encW,
                                               const float* __restrict__ decW,
                                               const float* __restrict__ outb,
                                               u8* __restrict__ ows,
                                               float* __restrict__ eob,
                                               float* __restrict__ wte,
                                               float* __restrict__ wtd) {
    long id = (long)blockIdx.x * 256 + threadIdx.x;
    const long n1 = (long)NPAD * KP / 4;         // u32 chunks
    if (id < n1) {
        int v = (int)(id / 80), k4 = (int)(id % 80) * 4;
        float4 f = {0.f, 0.f, 0.f, 0.f};
        if (v < VY && k4 < H) f = *(const float4*)&outW[(long)v * H + k4]; // k4<=296 -> full
        int w = __builtin_amdgcn_cvt_pk_fp8_f32(f.x, f.y, 0, false);
        w = __builtin_amdgcn_cvt_pk_fp8_f32(f.z, f.w, w, true);
        int laneb = (v & 15) + ((k4 >> 3) & 3) * 16;
        long dst = (long)(v >> 6) * 20480 + (k4 >> 5) * 2048 + ((v >> 5) & 1) * 1024
                 + (long)laneb * 16 + ((v >> 4) & 1) * 8 + (k4 & 7);
        *(unsigned int*)(ows + dst) = (unsigned int)w;
        return;
    }
    long id2 = id - n1;
    if (id2 < NPAD) {                            // eob: exp(bias), pad -> 0 (exp->*0)
        eob[id2] = (id2 < VY) ? __expf(outb[id2]) : 0.f;
        return;
    }
    id2 -= NPAD;
    if (id2 < 320L * KP) {                       // Wt_enc[k][j] = encW[j][k], 320 rows
        int k = (int)(id2 / KP), j = (int)(id2 % KP);
        wte[id2] = (k < H && j < H) ? encW[j * H + k] : 0.f;
        return;
    }
    id2 -= 320L * KP;
    if (id2 < 320L * KP) {                       // Wt_dec
        int k = (int)(id2 / KP), j = (int)(id2 % KP);
        wtd[id2] = (k < H && j < H) ? decW[j * H + k] : 0.f;
    }
}

// ---------------- K1: fdot2 recurrence + fused emb-producer waves ---------
// 256 blocks x 1024 threads.  Waves 0-9 (tid<640): the R7-proven fdot2 +
// part[] combine structure (k1 ~385us there).  Waves 10-15 (tid>=640, 320
// active): per step s, gather e(s+2) = emb[idx[s+2]] + bias into a 4-deep
// LDS ring; the ~600cy random-row gather latency lands inside the
// consumers' fdot2 phase instead of as a serial 65us k0b kernel (R7 lesson:
// PRE's k1 gain was exactly cancelled by k0b's serial cost).  Producers hit
// the SAME 2 barriers/step -- no flags, no deadlock risk.  Ring slot
// (s+2)&3 written at step s is read at step s+2 and last-read at s-2:
// always >=2 barriers of separation.
__global__ __launch_bounds__(1024) void k1_rnn(const int* __restrict__ x,
                                               const int* __restrict__ y,
                                               const float* __restrict__ enc_emb,
                                               const float* __restrict__ dec_emb,
                                               const float* __restrict__ encb,
                                               const float* __restrict__ decb,
                                               const float* __restrict__ wte,
                                               const float* __restrict__ wtd,
                                               u8* __restrict__ A8) {
    const int tid = threadIdx.x;
    const int b = blockIdx.x;
    const bool cons = tid < 640;                 // waves 0-9: recurrence
    const int s4 = cons ? tid / 160 : 0;         // k-slice 0..3
    const int j  = cons ? tid - s4 * 160 : 0;    // col pair base: cols j, j+160
    const bool comb = tid < 320;                 // combine threads, col jc
    const int jc = tid;
    const int pj = tid - 640;                    // producer col 0..383 (<320 active)

    __shared__ __align__(16) _Float16 hh[320];   // h (fp16), pad >=300 = 0
    __shared__ float part[1280];                 // [slice][col]
    __shared__ __align__(4) u8 a8row[320];
    __shared__ __align__(4) _Float16 ering[4][320];  // e ring (bias folded)

    if (comb) hh[jc] = (_Float16)0.f;

    // ---- consumer: encoder weights (2 cols x 40 pairs) ----
    f16x2 wa[40], wc[40];
    if (cons) {
#pragma unroll
        for (int kk = 0; kk < 40; ++kk) {
            int k0 = s4 * 80 + 2 * kk;
            wa[kk] = (f16x2){(_Float16)wte[k0 * KP + j],       (_Float16)wte[(k0 + 1) * KP + j]};
            wc[kk] = (f16x2){(_Float16)wte[k0 * KP + j + 160], (_Float16)wte[(k0 + 1) * KP + j + 160]};
        }
    }

    // ---- producer: per-col biases + prologue fill of ering[0..1] ----
    float bp_e = 0.f, bp_d = 0.f;
    if (!cons && pj < H) { bp_e = encb[pj]; bp_d = decb[pj]; }
    if (!cons && pj < 320) {
#pragma unroll
        for (int ss = 0; ss < 2; ++ss) {
            float ev = 0.f;
            if (pj < H) {
                int ix = x[ss * BATCH + b];
                ev = enc_emb[(long)ix * H + pj] + bp_e;
            }
            ering[ss][pj] = (_Float16)ev;
        }
    }
    __syncthreads();

    const f16x8* hb8 = (const f16x8*)&hh[s4 * 80];
    const int NS = NX + NY - 1;                  // 255 recurrence steps

#pragma unroll 1
    for (int s = 0; s < NS; ++s) {
        if (cons) {
            if (s == NX) {                       // one-time decoder weight reload
#pragma unroll
                for (int kk = 0; kk < 40; ++kk) {
                    int k0 = s4 * 80 + 2 * kk;
                    wa[kk] = (f16x2){(_Float16)wtd[k0 * KP + j],       (_Float16)wtd[(k0 + 1) * KP + j]};
                    wc[kk] = (f16x2){(_Float16)wtd[k0 * KP + j + 160], (_Float16)wtd[(k0 + 1) * KP + j + 160]};
                }
            }
            float p0 = 0.f, p1 = 0.f;
#pragma unroll
            for (int i = 0; i < 10; ++i) {
                f16x8 hv = hb8[i];
                f16x2 q0 = {hv[0], hv[1]}, q1 = {hv[2], hv[3]};
                f16x2 q2 = {hv[4], hv[5]}, q3 = {hv[6], hv[7]};
                p0 = __builtin_amdgcn_fdot2(wa[4 * i + 0], q0, p0, false);
                p1 = __builtin_amdgcn_fdot2(wc[4 * i + 0], q0, p1, false);
                p0 = __builtin_amdgcn_fdot2(wa[4 * i + 1], q1, p0, false);
                p1 = __builtin_amdgcn_fdot2(wc[4 * i + 1], q1, p1, false);
                p0 = __builtin_amdgcn_fdot2(wa[4 * i + 2], q2, p0, false);
                p1 = __builtin_amdgcn_fdot2(wc[4 * i + 2], q2, p1, false);
                p0 = __builtin_amdgcn_fdot2(wa[4 * i + 3], q3, p0, false);
                p1 = __builtin_amdgcn_fdot2(wc[4 * i + 3], q3, p1, false);
            }
            part[s4 * 320 + j] = p0;
            part[s4 * 320 + 160 + j] = p1;
        } else {
            int s2 = s + 2;                      // gather e(s+2) into the ring
            if (s2 < NS && pj < 320) {
                float ev = 0.f;
                if (pj < H) {
                    if (s2 < NX) {
                        int ix = x[s2 * BATCH + b];
                        ev = enc_emb[(long)ix * H + pj] + bp_e;
                    } else {
                        int iy = y[(s2 - NX) * BATCH + b];
                        ev = dec_emb[(long)iy * H + pj] + bp_d;
                    }
                }
                ering[s2 & 3][pj] = (_Float16)ev;
            }
        }
        __syncthreads();                         // B1: parts + ering(s) ready
        if (comb) {
            float v = part[jc] + part[320 + jc] + part[640 + jc] + part[960 + jc]
                    + (float)ering[s & 3][jc];
            v = fmaxf(v, 0.f);
            hh[jc] = (_Float16)v;
            if (s >= NX) {                       // decoder: fp8 row for A8
                int pk = __builtin_amdgcn_cvt_pk_fp8_f32(v, v, 0, false);
                a8row[jc] = (u8)(pk & 0xff);
            }
        }
        __syncthreads();                         // B2: h(s+1) + a8row ready
        if (s >= NX && tid < 80)                 // coalesced 320B row store
            ((unsigned int*)(A8 + (long)((s - NX) * BATCH + b) * KP))[tid] =
                ((const unsigned int*)a8row)[tid];
    }
}

// ---------------- K2: fp8 logits GEMM + exp row-sum, LDS-shared B ---------
// R3 known-good block structure + HALF-pipelined epilogue + R7 b128
// interleaved B-fragment reads (459us, MfmaUtil 65%; 3-blk/CU and full acc
// dbuf both spill -- measured; treat as locally optimal).
__global__ __launch_bounds__(256, 2) void k2_gemm(const u8* __restrict__ A8,
                                                  const u8* __restrict__ OWS,
                                                  const float* __restrict__ eob,
                                                  float* __restrict__ sumexp) {
    const int tid = threadIdx.x;
    const int lane = tid & 63, wave = tid >> 6;     // wave == row-slice
    const int lane16 = lane & 15, quad = lane >> 4;
    const int bid = blockIdx.x;
    const int cg8 = bid & 7;                        // 4096-col slice (XCD)
    const int cs  = (bid >> 3) & 3;                 // 1024-col sub-slice
    const int rb  = bid >> 5;                       // row block 0..126
    const int colbase = cg8 * 4096 + cs * 1024;
    const long tile0 = (long)(colbase >> 6);        // first 64-col tile

    __shared__ __align__(16) u8 bt[2][20480];       // double-buffered B tile

    // ---- A fragments -> registers (this wave's 64 rows x K=320)
    long a[4][10];
    {
        const u8* abase = A8 + ((long)rb * 256 + wave * 64 + lane16) * KP + quad * 8;
#pragma unroll
        for (int rt = 0; rt < 4; ++rt)
#pragma unroll
            for (int ks = 0; ks < 10; ++ks)
                a[rt][ks] = *(const long*)(abase + rt * 16 * KP + ks * 32);
    }

    // ---- prologue: stage tile 0 (linear copy; swizzle-agnostic)
    {
        const u8* src = OWS + tile0 * 20480 + (wave << 10) + (lane << 4);
        u8* dst = &bt[0][wave << 10];
#pragma unroll
        for (int r = 0; r < 5; ++r)
            ASYNC_COPY16(dst + r * 4096, src + r * 4096);
    }

    float rsum[16];
#pragma unroll
    for (int i = 0; i < 16; ++i) rsum[i] = 0.f;

    f32x4 accLo[4][2], accHi[4][2];

#pragma unroll 1
    for (int ct = 0; ct < 16; ++ct) {
        __syncthreads();                            // buf[ct&1] staged
        if (ct < 15) {                              // issue stage(ct+1) early
            const u8* src = OWS + (tile0 + ct + 1) * 20480 + (wave << 10) + (lane << 4);
            u8* dst = &bt[(ct + 1) & 1][wave << 10];
#pragma unroll
            for (int r = 0; r < 5; ++r)
                ASYNC_COPY16(dst + r * 4096, src + r * 4096);
        }
        const u8* bb = &bt[ct & 1][0];

        // ---- phase A: MFMA tc 0,1 -> accLo  (|| epilogue of prev accHi)
#pragma unroll
        for (int p = 0; p < 4; ++p)
#pragma unroll
            for (int q = 0; q < 2; ++q) accLo[p][q] = (f32x4){0.f, 0.f, 0.f, 0.f};
#pragma unroll
        for (int ks = 0; ks < 10; ++ks) {
            lx2 bp = *(const lx2*)(bb + ks * 2048 + lane * 16);   // tcp=0: tc0|tc1
#pragma unroll
            for (int rt = 0; rt < 4; ++rt) {
                accLo[rt][0] = __builtin_amdgcn_mfma_f32_16x16x32_fp8_fp8(
                    a[rt][ks], bp[0], accLo[rt][0], 0, 0, 0);
                accLo[rt][1] = __builtin_amdgcn_mfma_f32_16x16x32_fp8_fp8(
                    a[rt][ks], bp[1], accLo[rt][1], 0, 0, 0);
            }
        }
        if (ct > 0) {                               // prev ct, tc 2,3
            int cbp = colbase + (ct - 1) * 64;
#pragma unroll
            for (int tc = 0; tc < 2; ++tc) {
                float eb = eob[cbp + (tc + 2) * 16 + lane16];
#pragma unroll
                for (int rt = 0; rt < 4; ++rt)
#pragma unroll
                    for (int i = 0; i < 4; ++i)
                        rsum[rt * 4 + i] += __expf(accHi[rt][tc][i]) * eb;
            }
        }

        // ---- phase B: MFMA tc 2,3 -> accHi  (|| epilogue of this accLo)
#pragma unroll
        for (int p = 0; p < 4; ++p)
#pragma unroll
            for (int q = 0; q < 2; ++q) accHi[p][q] = (f32x4){0.f, 0.f, 0.f, 0.f};
#pragma unroll
        for (int ks = 0; ks < 10; ++ks) {
            lx2 bp = *(const lx2*)(bb + ks * 2048 + 1024 + lane * 16); // tcp=1: tc2|tc3
#pragma unroll
            for (int rt = 0; rt < 4; ++rt) {
                accHi[rt][0] = __builtin_amdgcn_mfma_f32_16x16x32_fp8_fp8(
                    a[rt][ks], bp[0], accHi[rt][0], 0, 0, 0);
                accHi[rt][1] = __builtin_amdgcn_mfma_f32_16x16x32_fp8_fp8(
                    a[rt][ks], bp[1], accHi[rt][1], 0, 0, 0);
            }
        }
        {                                           // this ct, tc 0,1
            int cb = colbase + ct * 64;
#pragma unroll
            for (int tc = 0; tc < 2; ++tc) {
                float eb = eob[cb + tc * 16 + lane16];
#pragma unroll
                for (int rt = 0; rt < 4; ++rt)
#pragma unroll
                    for (int i = 0; i < 4; ++i)
                        rsum[rt * 4 + i] += __expf(accLo[rt][tc][i]) * eb;
            }
        }
    }

    // final epilogue: ct = 15, tc 2,3 from accHi
    {
        int cb = colbase + 15 * 64;
#pragma unroll
        for (int tc = 0; tc < 2; ++tc) {
            float eb = eob[cb + (tc + 2) * 16 + lane16];
#pragma unroll
            for (int rt = 0; rt < 4; ++rt)
#pragma unroll
                for (int i = 0; i < 4; ++i)
                    rsum[rt * 4 + i] += __expf(accHi[rt][tc][i]) * eb;
        }
    }

    // reduce over 16 column-lanes; lane16==0 holds rows quad*4+i per rt
#pragma unroll
    for (int m = 1; m < 16; m <<= 1)
#pragma unroll
        for (int i = 0; i < 16; ++i) rsum[i] += __shfl_xor(rsum[i], m, 64);
    if (lane16 == 0) {
        float* sp = &sumexp[(long)rb * 256 + wave * 64];
#pragma unroll
        for (int rt = 0; rt < 4; ++rt)
#pragma unroll
            for (int i = 0; i < 4; ++i)
                atomicAdd(&sp[rt * 16 + quad * 4 + i], rsum[rt * 4 + i]);
    }
}

// ---------------- K3: target logit + CE + final reduce -------------------
// W target row from the interleaved OWS: lane l<40 -> (ks=l>>2, quad=l&3)
// u64 at tile(tgt) + ks*2048 + ((tgt>>5)&1)*1024
//        + ((tgt&15) + quad*16)*16 + ((tgt>>4)&1)*8.
__global__ __launch_bounds__(256) void k3_ce(const u8* __restrict__ A8,
                                             const u8* __restrict__ OWS,
                                             const float* __restrict__ outb,
                                             const float* __restrict__ sumexp,
                                             const int* __restrict__ y,
                                             float* __restrict__ out) {
    const int wave = threadIdx.x >> 6, lane = threadIdx.x & 63;
    const int r = blockIdx.x * 4 + wave;         // 0..32511
    const int t = r >> 8, b = r & 255;
    const int tgt = y[(t + 1) * BATCH + b];
    float s = 0.f;
    if (lane < 40) {
        unsigned long long av = *(const unsigned long long*)(A8 + (long)r * KP + lane * 8);
        int laneb = (tgt & 15) + (lane & 3) * 16;
        long wdst = (long)(tgt >> 6) * 20480 + (lane >> 2) * 2048
                  + ((tgt >> 5) & 1) * 1024 + (long)laneb * 16 + ((tgt >> 4) & 1) * 8;
        unsigned long long wv = *(const unsigned long long*)(OWS + wdst);
        unsigned int a4 = (unsigned int)av, a4h = (unsigned int)(av >> 32);
        unsigned int w4 = (unsigned int)wv, w4h = (unsigned int)(wv >> 32);
        f32x2 al = __builtin_amdgcn_cvt_pk_f32_fp8(a4, false);
        f32x2 ah = __builtin_amdgcn_cvt_pk_f32_fp8(a4, true);
        f32x2 wl = __builtin_amdgcn_cvt_pk_f32_fp8(w4, false);
        f32x2 wh = __builtin_amdgcn_cvt_pk_f32_fp8(w4, true);
        s += al[0] * wl[0] + al[1] * wl[1] + ah[0] * wh[0] + ah[1] * wh[1];
        al = __builtin_amdgcn_cvt_pk_f32_fp8(a4h, false);
        ah = __builtin_amdgcn_cvt_pk_f32_fp8(a4h, true);
        wl = __builtin_amdgcn_cvt_pk_f32_fp8(w4h, false);
        wh = __builtin_amdgcn_cvt_pk_f32_fp8(w4h, true);
        s += al[0] * wl[0] + al[1] * wl[1] + ah[0] * wh[0] + ah[1] * wh[1];
    }
#pragma unroll
    for (int m = 1; m < 64; m <<= 1) s += __shfl_xor(s, m, 64);
    __shared__ float part[4];
    if (lane == 0) part[wave] = logf(sumexp[r]) - (s + outb[tgt]);
    __syncthreads();
    if (threadIdx.x == 0) {
        float tot = part[0] + part[1] + part[2] + part[3];
        atomicAdd(out, tot * (1.0f / 256.0f));
    }
}

// ---------------- launch --------------------------------------------------
extern "C" void kernel_launch(void* const* d_in, const int* in_sizes, int n_in,
                              void* d_out, int out_size, void* d_ws, size_t ws_size,
                              hipStream_t stream) {
    (void)in_sizes; (void)n_in; (void)out_size; (void)ws_size;
    const int*   x       = (const int*)d_in[0];
    const int*   y       = (const int*)d_in[1];
    const float* enc_emb = (const float*)d_in[2];
    const float* encW    = (const float*)d_in[3];
    const float* encb    = (const float*)d_in[4];
    const float* dec_emb = (const float*)d_in[5];
    const float* decW    = (const float*)d_in[6];
    const float* decb    = (const float*)d_in[7];
    const float* outW    = (const float*)d_in[8];
    const float* outb    = (const float*)d_in[9];

    char* ws = (char*)d_ws;
    u8* ows  = (u8*)(ws + OWS_OFF);
    u8* A8   = (u8*)(ws + A8_OFF);
    float* wte    = (float*)(ws + WTE_OFF);
    float* wtd    = (float*)(ws + WTD_OFF);
    float* eob    = (float*)(ws + OBP_OFF);
    float* sumexp = (float*)(ws + SE_OFF);

    hipMemsetAsync(sumexp, 0, SE_BYTES, stream);
    hipMemsetAsync(d_out, 0, sizeof(float), stream);

    long n0 = (long)NPAD * KP / 4 + NPAD + 2L * 320 * KP;
    k0_prep<<<(int)((n0 + 255) / 256), 256, 0, stream>>>(outW, encW, decW, outb,
                                                         ows, eob, wte, wtd);
    k1_rnn<<<256, 1024, 0, stream>>>(x, y, enc_emb, dec_emb, encb, decb,
                                     wte, wtd, A8);
    k2_gemm<<<127 * 32, 256, 0, stream>>>(A8, ows, eob, sumexp);
    k3_ce<<<8128, 256, 0, stream>>>(A8, ows, outb, sumexp, y, (float*)d_out);
}

// Round 10
// 955.121 us; speedup vs baseline: 4.2876x; 4.2876x over previous
//
#include <hip/hip_runtime.h>
#include <hip/hip_bf16.h>
#include <stdint.h>

typedef unsigned short u16;
typedef unsigned char u8;
typedef float f32x4 __attribute__((ext_vector_type(4)));
typedef float f32x2 __attribute__((ext_vector_type(2)));
typedef _Float16 f16x2 __attribute__((ext_vector_type(2)));
typedef _Float16 f16x8 __attribute__((ext_vector_type(8)));
typedef long lx2 __attribute__((ext_vector_type(2)));

#define H      300
#define KP     320          // K padded (320 fp8 bytes per row)
#define BATCH  256
#define NX     128
#define NY     128
#define VY     32000
#define NPAD   32768        // vocab padded
#define MROWS  32512        // 127*256 decoder rows

// Swizzled OW layout (OWS), tc-pair INTERLEAVED: vocab col v, k ->
// tile = v>>6 (64 cols x 320 K = 20480 B each); within tile:
//   byte = (k>>5)*2048 + ((v>>5)&1)*1024
//        + ((v&15) + ((k>>3)&3)*16)*16 + ((v>>4)&1)*8 + (k&7)
// A lane's ds_read_b128 at [ks*2048 + tcp*1024 + lane*16] returns the b64
// MFMA B-fragments of BOTH tc=2*tcp and tc=2*tcp+1.
// Staging remains a LINEAR 20480B tile copy (swizzle-agnostic).

// workspace layout (bytes)
#define OWS_OFF   0UL
#define OWS_BYTES ((unsigned long)NPAD * KP)           // 10,485,760
#define OWS_PAD   131072UL
#define A8_OFF    (OWS_OFF + OWS_BYTES + OWS_PAD)
#define A8_BYTES  ((unsigned long)MROWS * KP)          // 10,403,840
#define WTE_OFF   (A8_OFF + A8_BYTES)
#define WT_BYTES  (320UL * KP * 4)                     // 320 rows (zero-pad k>=300)
#define WTD_OFF   (WTE_OFF + WT_BYTES)
#define OBP_OFF   (WTD_OFF + WT_BYTES)
#define OBP_BYTES ((unsigned long)NPAD * 4)            // eob = exp(outb), pad = 0
#define SE_OFF    (OBP_OFF + OBP_BYTES)
#define SE_BYTES  ((unsigned long)MROWS * 4)

// async 16B global -> LDS copy (LDS dst is wave-uniform base; HW adds lane*16)
#define ASYNC_COPY16(dst_lds, src_glb)                                          \
    __builtin_amdgcn_global_load_lds(                                           \
        (const __attribute__((address_space(1))) unsigned int*)(src_glb),       \
        (__attribute__((address_space(3))) unsigned int*)(dst_lds), 16, 0, 0)

// ---------------- K0: prep (fp8 outW -> swizzled OWS; eob; W^T) ----------
__global__ __launch_bounds__(256) void k0_prep(const float* __restrict__ outW,
                                               const float* __restrict__ encW,
                                               const float* __restrict__ decW,
                                               const float* __restrict__ outb,
                                               u8* __restrict__ ows,
                                               float* __restrict__ eob,
                                               float* __restrict__ wte,
                                               float* __restrict__ wtd) {
    long id = (long)blockIdx.x * 256 + threadIdx.x;
    const long n1 = (long)NPAD * KP / 4;         // u32 chunks
    if (id < n1) {
        int v = (int)(id / 80), k4 = (int)(id % 80) * 4;
        float4 f = {0.f, 0.f, 0.f, 0.f};
        if (v < VY && k4 < H) f = *(const float4*)&outW[(long)v * H + k4]; // k4<=296 -> full
        int w = __builtin_amdgcn_cvt_pk_fp8_f32(f.x, f.y, 0, false);
        w = __builtin_amdgcn_cvt_pk_fp8_f32(f.z, f.w, w, true);
        int laneb = (v & 15) + ((k4 >> 3) & 3) * 16;
        long dst = (long)(v >> 6) * 20480 + (k4 >> 5) * 2048 + ((v >> 5) & 1) * 1024
                 + (long)laneb * 16 + ((v >> 4) & 1) * 8 + (k4 & 7);
        *(unsigned int*)(ows + dst) = (unsigned int)w;
        return;
    }
    long id2 = id - n1;
    if (id2 < NPAD) {                            // eob: exp(bias), pad -> 0 (exp->*0)
        eob[id2] = (id2 < VY) ? __expf(outb[id2]) : 0.f;
        return;
    }
    id2 -= NPAD;
    if (id2 < 320L * KP) {                       // Wt_enc[k][j] = encW[j][k], 320 rows
        int k = (int)(id2 / KP), j = (int)(id2 % KP);
        wte[id2] = (k < H && j < H) ? encW[j * H + k] : 0.f;
        return;
    }
    id2 -= 320L * KP;
    if (id2 < 320L * KP) {                       // Wt_dec
        int k = (int)(id2 / KP), j = (int)(id2 % KP);
        wtd[id2] = (k < H && j < H) ? decW[j * H + k] : 0.f;
    }
}

// ---------------- K1: register-resident weights, 1 batch elem / block ----
// The R0-R3 proven structure (430-440us, absmax=0 across 4 rounds).  256
// blocks x 640 threads (10 waves).  Thread (s=tid/160, j=tid%160) holds
// W[:, {j, j+160}] for k in [80s, 80s+80) as 80 packed f16 pairs; each b128
// h-broadcast read feeds 8 fdot2 (2 cols x 4 pairs).  Every restructure
// attempted in R4-R9 (MFMA tile, in-wave shuffle, PRE+k0b, fused producer
// waves) measured WORSE -- __syncthreads drains vmcnt(0), so cross-barrier
// prefetch is impossible and the alternatives paid more in spill/latency/
// serial-prep than they saved.  This is the empirical optimum of the arc.
__global__ __launch_bounds__(640) void k1_rnn(const int* __restrict__ x,
                                              const int* __restrict__ y,
                                              const float* __restrict__ enc_emb,
                                              const float* __restrict__ dec_emb,
                                              const float* __restrict__ encb,
                                              const float* __restrict__ decb,
                                              const float* __restrict__ wte,
                                              const float* __restrict__ wtd,
                                              u8* __restrict__ A8) {
    const int tid = threadIdx.x;
    const int s = tid / 160;           // k-slice 0..3
    const int j = tid - s * 160;       // column pair base: cols j, j+160
    const int b = blockIdx.x;

    __shared__ __align__(16) _Float16 hh[320];   // h (fp16), pad >=300 = 0
    __shared__ float part[1280];                 // [slice][col]
    __shared__ __align__(4) u8 a8row[320];

    for (int i = tid; i < 320; i += 640) hh[i] = (_Float16)0.f;

    const bool comb = (tid < 320);     // combine-phase threads, col jc
    const int jc = tid;
    const float be = (comb && jc < H) ? encb[jc] : 0.f;
    const float bd = (comb && jc < H) ? decb[jc] : 0.f;

    // ---- preload encoder weights (2 cols x 40 pairs) ----
    f16x2 wa[40], wc[40];
#pragma unroll
    for (int kk = 0; kk < 40; ++kk) {
        int k0 = s * 80 + 2 * kk;
        wa[kk] = (f16x2){(_Float16)wte[k0 * KP + j],       (_Float16)wte[(k0 + 1) * KP + j]};
        wc[kk] = (f16x2){(_Float16)wte[k0 * KP + j + 160], (_Float16)wte[(k0 + 1) * KP + j + 160]};
    }

    // ---- encoder: 128 steps ----
    int idx_n = x[BATCH + b];
    float e_cur = 0.f;
    if (comb && jc < H) e_cur = enc_emb[(long)x[b] * H + jc];
    __syncthreads();

    const f16x8* hb8 = (const f16x8*)&hh[s * 80];

    for (int t = 0; t < NX; ++t) {
        int idx_n2 = x[min(t + 2, NX - 1) * BATCH + b];
        float e_nx = 0.f;
        if (comb && jc < H && t + 1 < NX) e_nx = enc_emb[(long)idx_n * H + jc];

        float p0 = 0.f, p1 = 0.f;
#pragma unroll
        for (int i = 0; i < 10; ++i) {
            f16x8 hv = hb8[i];
            f16x2 q0 = {hv[0], hv[1]}, q1 = {hv[2], hv[3]};
            f16x2 q2 = {hv[4], hv[5]}, q3 = {hv[6], hv[7]};
            p0 = __builtin_amdgcn_fdot2(wa[4 * i + 0], q0, p0, false);
            p1 = __builtin_amdgcn_fdot2(wc[4 * i + 0], q0, p1, false);
            p0 = __builtin_amdgcn_fdot2(wa[4 * i + 1], q1, p0, false);
            p1 = __builtin_amdgcn_fdot2(wc[4 * i + 1], q1, p1, false);
            p0 = __builtin_amdgcn_fdot2(wa[4 * i + 2], q2, p0, false);
            p1 = __builtin_amdgcn_fdot2(wc[4 * i + 2], q2, p1, false);
            p0 = __builtin_amdgcn_fdot2(wa[4 * i + 3], q3, p0, false);
            p1 = __builtin_amdgcn_fdot2(wc[4 * i + 3], q3, p1, false);
        }
        part[s * 320 + j] = p0;
        part[s * 320 + 160 + j] = p1;
        __syncthreads();
        if (comb) {
            float v = part[jc] + part[320 + jc] + part[640 + jc] + part[960 + jc] + be + e_cur;
            hh[jc] = (_Float16)fmaxf(v, 0.f);
        }
        __syncthreads();
        e_cur = e_nx; idx_n = idx_n2;
    }

    // ---- reload decoder weights ----
#pragma unroll
    for (int kk = 0; kk < 40; ++kk) {
        int k0 = s * 80 + 2 * kk;
        wa[kk] = (f16x2){(_Float16)wtd[k0 * KP + j],       (_Float16)wtd[(k0 + 1) * KP + j]};
        wc[kk] = (f16x2){(_Float16)wtd[k0 * KP + j + 160], (_Float16)wtd[(k0 + 1) * KP + j + 160]};
    }

    // ---- decoder: 127 steps; fp8 h rows -> A8 via coalesced u32 ----
    idx_n = y[BATCH + b];
    e_cur = 0.f;
    if (comb && jc < H) e_cur = dec_emb[(long)y[b] * H + jc];

    for (int t = 0; t < NY - 1; ++t) {
        int idx_n2 = y[min(t + 2, NY - 1) * BATCH + b];
        float e_nx = 0.f;
        if (comb && jc < H && t + 1 < NY - 1) e_nx = dec_emb[(long)idx_n * H + jc];

        float p0 = 0.f, p1 = 0.f;
#pragma unroll
        for (int i = 0; i < 10; ++i) {
            f16x8 hv = hb8[i];
            f16x2 q0 = {hv[0], hv[1]}, q1 = {hv[2], hv[3]};
            f16x2 q2 = {hv[4], hv[5]}, q3 = {hv[6], hv[7]};
            p0 = __builtin_amdgcn_fdot2(wa[4 * i + 0], q0, p0, false);
            p1 = __builtin_amdgcn_fdot2(wc[4 * i + 0], q0, p1, false);
            p0 = __builtin_amdgcn_fdot2(wa[4 * i + 1], q1, p0, false);
            p1 = __builtin_amdgcn_fdot2(wc[4 * i + 1], q1, p1, false);
            p0 = __builtin_amdgcn_fdot2(wa[4 * i + 2], q2, p0, false);
            p1 = __builtin_amdgcn_fdot2(wc[4 * i + 2], q2, p1, false);
            p0 = __builtin_amdgcn_fdot2(wa[4 * i + 3], q3, p0, false);
            p1 = __builtin_amdgcn_fdot2(wc[4 * i + 3], q3, p1, false);
        }
        part[s * 320 + j] = p0;
        part[s * 320 + 160 + j] = p1;
        __syncthreads();
        if (comb) {
            float v = part[jc] + part[320 + jc] + part[640 + jc] + part[960 + jc] + bd + e_cur;
            v = fmaxf(v, 0.f);
            hh[jc] = (_Float16)v;
            int pk = __builtin_amdgcn_cvt_pk_fp8_f32(v, v, 0, false);
            a8row[jc] = (u8)(pk & 0xff);
        }
        __syncthreads();
        if (tid < 80)   // coalesced 320B row store
            ((unsigned int*)(A8 + (long)(t * BATCH + b) * KP))[tid] =
                ((const unsigned int*)a8row)[tid];
        e_cur = e_nx; idx_n = idx_n2;
    }
}

// ---------------- K2: fp8 logits GEMM + exp row-sum, LDS-shared B ---------
// Best measured k2 (459.5us, MfmaUtil 65%): LDS-shared B tile (4x L2 reuse),
// HALF-pipelined exp epilogue (accLo/accHi), b128 interleaved B-fragment
// reads, 2 blocks/CU.  Measured dead ends: 3 blk/CU (VGPR cap 84 -> spill),
// full acc double-buffer (spill), quarter-phase @3blk (spill).
__global__ __launch_bounds__(256, 2) void k2_gemm(const u8* __restrict__ A8,
                                                  const u8* __restrict__ OWS,
                                                  const float* __restrict__ eob,
                                                  float* __restrict__ sumexp) {
    const int tid = threadIdx.x;
    const int lane = tid & 63, wave = tid >> 6;     // wave == row-slice
    const int lane16 = lane & 15, quad = lane >> 4;
    const int bid = blockIdx.x;
    const int cg8 = bid & 7;                        // 4096-col slice (XCD)
    const int cs  = (bid >> 3) & 3;                 // 1024-col sub-slice
    const int rb  = bid >> 5;                       // row block 0..126
    const int colbase = cg8 * 4096 + cs * 1024;
    const long tile0 = (long)(colbase >> 6);        // first 64-col tile

    __shared__ __align__(16) u8 bt[2][20480];       // double-buffered B tile

    // ---- A fragments -> registers (this wave's 64 rows x K=320)
    long a[4][10];
    {
        const u8* abase = A8 + ((long)rb * 256 + wave * 64 + lane16) * KP + quad * 8;
#pragma unroll
        for (int rt = 0; rt < 4; ++rt)
#pragma unroll
            for (int ks = 0; ks < 10; ++ks)
                a[rt][ks] = *(const long*)(abase + rt * 16 * KP + ks * 32);
    }

    // ---- prologue: stage tile 0 (linear copy; swizzle-agnostic)
    {
        const u8* src = OWS + tile0 * 20480 + (wave << 10) + (lane << 4);
        u8* dst = &bt[0][wave << 10];
#pragma unroll
        for (int r = 0; r < 5; ++r)
            ASYNC_COPY16(dst + r * 4096, src + r * 4096);
    }

    float rsum[16];
#pragma unroll
    for (int i = 0; i < 16; ++i) rsum[i] = 0.f;

    f32x4 accLo[4][2], accHi[4][2];

#pragma unroll 1
    for (int ct = 0; ct < 16; ++ct) {
        __syncthreads();                            // buf[ct&1] staged
        if (ct < 15) {                              // issue stage(ct+1) early
            const u8* src = OWS + (tile0 + ct + 1) * 20480 + (wave << 10) + (lane << 4);
            u8* dst = &bt[(ct + 1) & 1][wave << 10];
#pragma unroll
            for (int r = 0; r < 5; ++r)
                ASYNC_COPY16(dst + r * 4096, src + r * 4096);
        }
        const u8* bb = &bt[ct & 1][0];

        // ---- phase A: MFMA tc 0,1 -> accLo  (|| epilogue of prev accHi)
#pragma unroll
        for (int p = 0; p < 4; ++p)
#pragma unroll
            for (int q = 0; q < 2; ++q) accLo[p][q] = (f32x4){0.f, 0.f, 0.f, 0.f};
#pragma unroll
        for (int ks = 0; ks < 10; ++ks) {
            lx2 bp = *(const lx2*)(bb + ks * 2048 + lane * 16);   // tcp=0: tc0|tc1
#pragma unroll
            for (int rt = 0; rt < 4; ++rt) {
                accLo[rt][0] = __builtin_amdgcn_mfma_f32_16x16x32_fp8_fp8(
                    a[rt][ks], bp[0], accLo[rt][0], 0, 0, 0);
                accLo[rt][1] = __builtin_amdgcn_mfma_f32_16x16x32_fp8_fp8(
                    a[rt][ks], bp[1], accLo[rt][1], 0, 0, 0);
            }
        }
        if (ct > 0) {                               // prev ct, tc 2,3
            int cbp = colbase + (ct - 1) * 64;
#pragma unroll
            for (int tc = 0; tc < 2; ++tc) {
                float eb = eob[cbp + (tc + 2) * 16 + lane16];
#pragma unroll
                for (int rt = 0; rt < 4; ++rt)
#pragma unroll
                    for (int i = 0; i < 4; ++i)
                        rsum[rt * 4 + i] += __expf(accHi[rt][tc][i]) * eb;
            }
        }

        // ---- phase B: MFMA tc 2,3 -> accHi  (|| epilogue of this accLo)
#pragma unroll
        for (int p = 0; p < 4; ++p)
#pragma unroll
            for (int q = 0; q < 2; ++q) accHi[p][q] = (f32x4){0.f, 0.f, 0.f, 0.f};
#pragma unroll
        for (int ks = 0; ks < 10; ++ks) {
            lx2 bp = *(const lx2*)(bb + ks * 2048 + 1024 + lane * 16); // tcp=1: tc2|tc3
#pragma unroll
            for (int rt = 0; rt < 4; ++rt) {
                accHi[rt][0] = __builtin_amdgcn_mfma_f32_16x16x32_fp8_fp8(
                    a[rt][ks], bp[0], accHi[rt][0], 0, 0, 0);
                accHi[rt][1] = __builtin_amdgcn_mfma_f32_16x16x32_fp8_fp8(
                    a[rt][ks], bp[1], accHi[rt][1], 0, 0, 0);
            }
        }
        {                                           // this ct, tc 0,1
            int cb = colbase + ct * 64;
#pragma unroll
            for (int tc = 0; tc < 2; ++tc) {
                float eb = eob[cb + tc * 16 + lane16];
#pragma unroll
                for (int rt = 0; rt < 4; ++rt)
#pragma unroll
                    for (int i = 0; i < 4; ++i)
                        rsum[rt * 4 + i] += __expf(accLo[rt][tc][i]) * eb;
            }
        }
    }

    // final epilogue: ct = 15, tc 2,3 from accHi
    {
        int cb = colbase + 15 * 64;
#pragma unroll
        for (int tc = 0; tc < 2; ++tc) {
            float eb = eob[cb + (tc + 2) * 16 + lane16];
#pragma unroll
            for (int rt = 0; rt < 4; ++rt)
#pragma unroll
                for (int i = 0; i < 4; ++i)
                    rsum[rt * 4 + i] += __expf(accHi[rt][tc][i]) * eb;
        }
    }

    // reduce over 16 column-lanes; lane16==0 holds rows quad*4+i per rt
#pragma unroll
    for (int m = 1; m < 16; m <<= 1)
#pragma unroll
        for (int i = 0; i < 16; ++i) rsum[i] += __shfl_xor(rsum[i], m, 64);
    if (lane16 == 0) {
        float* sp = &sumexp[(long)rb * 256 + wave * 64];
#pragma unroll
        for (int rt = 0; rt < 4; ++rt)
#pragma unroll
            for (int i = 0; i < 4; ++i)
                atomicAdd(&sp[rt * 16 + quad * 4 + i], rsum[rt * 4 + i]);
    }
}

// ---------------- K3: target logit + CE + final reduce -------------------
// W target row from the interleaved OWS: lane l<40 -> (ks=l>>2, quad=l&3)
// u64 at tile(tgt) + ks*2048 + ((tgt>>5)&1)*1024
//        + ((tgt&15) + quad*16)*16 + ((tgt>>4)&1)*8.
__global__ __launch_bounds__(256) void k3_ce(const u8* __restrict__ A8,
                                             const u8* __restrict__ OWS,
                                             const float* __restrict__ outb,
                                             const float* __restrict__ sumexp,
                                             const int* __restrict__ y,
                                             float* __restrict__ out) {
    const int wave = threadIdx.x >> 6, lane = threadIdx.x & 63;
    const int r = blockIdx.x * 4 + wave;         // 0..32511
    const int t = r >> 8, b = r & 255;
    const int tgt = y[(t + 1) * BATCH + b];
    float s = 0.f;
    if (lane < 40) {
        unsigned long long av = *(const unsigned long long*)(A8 + (long)r * KP + lane * 8);
        int laneb = (tgt & 15) + (lane & 3) * 16;
        long wdst = (long)(tgt >> 6) * 20480 + (lane >> 2) * 2048
                  + ((tgt >> 5) & 1) * 1024 + (long)laneb * 16 + ((tgt >> 4) & 1) * 8;
        unsigned long long wv = *(const unsigned long long*)(OWS + wdst);
        unsigned int a4 = (unsigned int)av, a4h = (unsigned int)(av >> 32);
        unsigned int w4 = (unsigned int)wv, w4h = (unsigned int)(wv >> 32);
        f32x2 al = __builtin_amdgcn_cvt_pk_f32_fp8(a4, false);
        f32x2 ah = __builtin_amdgcn_cvt_pk_f32_fp8(a4, true);
        f32x2 wl = __builtin_amdgcn_cvt_pk_f32_fp8(w4, false);
        f32x2 wh = __builtin_amdgcn_cvt_pk_f32_fp8(w4, true);
        s += al[0] * wl[0] + al[1] * wl[1] + ah[0] * wh[0] + ah[1] * wh[1];
        al = __builtin_amdgcn_cvt_pk_f32_fp8(a4h, false);
        ah = __builtin_amdgcn_cvt_pk_f32_fp8(a4h, true);
        wl = __builtin_amdgcn_cvt_pk_f32_fp8(w4h, false);
        wh = __builtin_amdgcn_cvt_pk_f32_fp8(w4h, true);
        s += al[0] * wl[0] + al[1] * wl[1] + ah[0] * wh[0] + ah[1] * wh[1];
    }
#pragma unroll
    for (int m = 1; m < 64; m <<= 1) s += __shfl_xor(s, m, 64);
    __shared__ float part[4];
    if (lane == 0) part[wave] = logf(sumexp[r]) - (s + outb[tgt]);
    __syncthreads();
    if (threadIdx.x == 0) {
        float tot = part[0] + part[1] + part[2] + part[3];
        atomicAdd(out, tot * (1.0f / 256.0f));
    }
}

// ---------------- launch --------------------------------------------------
extern "C" void kernel_launch(void* const* d_in, const int* in_sizes, int n_in,
                              void* d_out, int out_size, void* d_ws, size_t ws_size,
                              hipStream_t stream) {
    (void)in_sizes; (void)n_in; (void)out_size; (void)ws_size;
    const int*   x       = (const int*)d_in[0];
    const int*   y       = (const int*)d_in[1];
    const float* enc_emb = (const float*)d_in[2];
    const float* encW    = (const float*)d_in[3];
    const float* encb    = (const float*)d_in[4];
    const float* dec_emb = (const float*)d_in[5];
    const float* decW    = (const float*)d_in[6];
    const float* decb    = (const float*)d_in[7];
    const float* outW    = (const float*)d_in[8];
    const float* outb    = (const float*)d_in[9];

    char* ws = (char*)d_ws;
    u8* ows  = (u8*)(ws + OWS_OFF);
    u8* A8   = (u8*)(ws + A8_OFF);
    float* wte    = (float*)(ws + WTE_OFF);
    float* wtd    = (float*)(ws + WTD_OFF);
    float* eob    = (float*)(ws + OBP_OFF);
    float* sumexp = (float*)(ws + SE_OFF);

    hipMemsetAsync(sumexp, 0, SE_BYTES, stream);
    hipMemsetAsync(d_out, 0, sizeof(float), stream);

    long n0 = (long)NPAD * KP / 4 + NPAD + 2L * 320 * KP;
    k0_prep<<<(int)((n0 + 255) / 256), 256, 0, stream>>>(outW, encW, decW, outb,
                                                         ows, eob, wte, wtd);
    k1_rnn<<<256, 640, 0, stream>>>(x, y, enc_emb, dec_emb, encb, decb, wte, wtd, A8);
    k2_gemm<<<127 * 32, 256, 0, stream>>>(A8, ows, eob, sumexp);
    k3_ce<<<8128, 256, 0, stream>>>(A8, ows, outb, sumexp, y, (float*)d_out);
}